// Round 8
// baseline (268.292 us; speedup 1.0000x reference)
//
#include <hip/hip_runtime.h>
#include <math.h>

#define NN 20000
#define NE 320000
#define NREL 9
#define NBASES 9
#define D_IN 128
#define D_HID 256
#define D_OUT 64
#define LN_EPS 1e-5f

#define N1 (NREL * D_HID + D_HID)   // 2560
#define N2 (NREL * D_OUT + D_OUT)   // 640
#define NBLK ((NN + 255) / 256)     // 79

typedef __attribute__((ext_vector_type(8))) short bf16x8;
typedef __attribute__((ext_vector_type(4))) float f32x4;

__device__ inline ushort f2b(float f) {
    unsigned u = __float_as_uint(f);
    return (ushort)((u + 0x7FFFu + ((u >> 16) & 1u)) >> 16);
}
__device__ inline float b2f(ushort h) { return __uint_as_float(((unsigned)h) << 16); }
__device__ inline unsigned pack2bf(float f0, float f1) {
    return (unsigned)f2b(f0) | ((unsigned)f2b(f1) << 16);
}

// ---------- fused prep: w1t, w2t (basis-combined, transposed, bf16) + x cast ----------
__global__ __launch_bounds__(256) void prep_all(
    const float* __restrict__ bases1, const float* __restrict__ comp1, const float* __restrict__ root1,
    const float* __restrict__ bases2, const float* __restrict__ comp2, const float* __restrict__ root2,
    const float* __restrict__ x,
    ushort* __restrict__ w1t, ushort* __restrict__ w2t, ushort* __restrict__ xbf)
{
    const int SZ1 = N1 * D_IN;
    const int SZ2 = N2 * D_HID;
    const int SZX = NN * D_IN;
    int tid = blockIdx.x * 256 + threadIdx.x;
    if (tid < SZ1) {
        int n = tid >> 7, k = tid & 127;
        float s;
        if (n < NREL * D_HID) {
            int r = n >> 8, o = n & 255;
            s = 0.f;
            #pragma unroll
            for (int b = 0; b < NBASES; b++)
                s += comp1[r * NBASES + b] * bases1[(b * D_IN + k) * D_HID + o];
        } else {
            s = root1[k * D_HID + (n - NREL * D_HID)];
        }
        w1t[tid] = f2b(s);
    } else if (tid < SZ1 + SZ2) {
        int j = tid - SZ1;
        int n = j >> 8, k = j & 255;
        float s;
        if (n < NREL * D_OUT) {
            int r = n >> 6, o = n & 63;
            s = 0.f;
            #pragma unroll
            for (int b = 0; b < NBASES; b++)
                s += comp2[r * NBASES + b] * bases2[(b * D_HID + k) * D_OUT + o];
        } else {
            s = root2[k * D_OUT + (n - NREL * D_OUT)];
        }
        w2t[j] = f2b(s);
    } else if (tid < SZ1 + SZ2 + SZX) {
        int j = tid - SZ1 - SZ2;
        xbf[j] = f2b(x[j]);
    }
}

// ---------- CSR build ----------
__global__ __launch_bounds__(256) void hist_dst(const int* __restrict__ dst, int* __restrict__ deg)
{
    int e = blockIdx.x * 256 + threadIdx.x;
    if (e < NE) atomicAdd(&deg[dst[e]], 1);
}

__global__ __launch_bounds__(256) void scan_blk(
    const int* __restrict__ deg, int* __restrict__ local, int* __restrict__ bsum)
{
    __shared__ int wsum[4];
    int tid = threadIdx.x, lane = tid & 63, w = tid >> 6;
    int i = blockIdx.x * 256 + tid;
    int v = (i < NN) ? deg[i] : 0;
    int x = v;
    #pragma unroll
    for (int d = 1; d < 64; d <<= 1) {
        int y = __shfl_up(x, d, 64);
        if (lane >= d) x += y;
    }
    if (lane == 63) wsum[w] = x;
    __syncthreads();
    int woff = 0;
    for (int j = 0; j < w; j++) woff += wsum[j];
    if (i < NN) local[i] = woff + x - v;
    if (tid == 255) bsum[blockIdx.x] = woff + x;
}

// finalize: each block redundantly top-scans the 79 block sums (1 wave), then
// adds; removes the separate scan_top launch. offs[NN] == NE by construction.
__global__ __launch_bounds__(256) void scan_fin(
    const int* __restrict__ local, const int* __restrict__ bsum,
    int* __restrict__ offs, int* __restrict__ cursor)
{
    __shared__ int boff_s[NBLK];
    int tid = threadIdx.x;
    if (tid < 64) {
        int carry = 0;
        for (int base = 0; base < NBLK; base += 64) {
            int i = base + tid;
            int v = (i < NBLK) ? bsum[i] : 0;
            int x = v;
            #pragma unroll
            for (int d = 1; d < 64; d <<= 1) {
                int y = __shfl_up(x, d, 64);
                if (tid >= d) x += y;
            }
            if (i < NBLK) boff_s[i] = carry + x - v;
            carry += __shfl(x, 63, 64);
        }
    }
    __syncthreads();
    int i = blockIdx.x * 256 + tid;
    if (i < NN) {
        int o = local[i] + boff_s[i >> 8];
        offs[i] = o;
        cursor[i] = o;
    }
    if (i == NN) offs[NN] = NE;
}

__global__ __launch_bounds__(256) void scatter_ep(
    const int* __restrict__ src, const int* __restrict__ dst, const int* __restrict__ etype,
    int* __restrict__ cursor, int* __restrict__ ep1, int* __restrict__ ep2)
{
    int e = blockIdx.x * 256 + threadIdx.x;
    if (e >= NE) return;
    int d = dst[e];
    int s = src[e], r = etype[e];
    int pos = atomicAdd(&cursor[d], 1);
    ep1[pos] = s * N1 + r * D_HID;
    ep2[pos] = s * N2 + r * D_OUT;
}

// ---------- bf16 MFMA GEMM: C[M][N] = A[M][K] @ Bt[N][K]^T ----------
// 128x128 tile, BK=32, double-buffered LDS (one barrier per chunk), VGPR
// staging (loads of chunk c+1 overlap MFMA of chunk c). LDS is in MFMA
// fragment order: slot s (16 B) = tile (s>>6), lane (s&63); writer thread t
// fills slots t and t+256 -> consecutive lanes write consecutive 16 B
// (0 conflicts, measured r5/r6); reader frag = (tile*64+lane)*16 B
// (0 conflicts). Slot decode: g=s>>6 (16-row group), kc=(s>>4)&3, mr=s&15.
// Operand-swapped MFMA -> C^T tiles -> packed uint2 stores.
__global__ __launch_bounds__(256) void gemm_bf16(
    const ushort* __restrict__ A, const ushort* __restrict__ Bt, ushort* __restrict__ C,
    int M, int N, int K)
{
    __shared__ ushort As[2][512 * 8];   // 8 KB per buffer
    __shared__ ushort Bs[2][512 * 8];   // 32 KB total

    int tid = threadIdx.x;
    int lane = tid & 63, w = tid >> 6;
    int wm = w >> 1, wn = w & 1;
    int row0 = blockIdx.y * 128, col0 = blockIdx.x * 128;

    // writer: thread t owns slots t (s0) and t+256 (s1)
    int s0 = tid, s1 = tid + 256;
    int g0 = s0 >> 6, kc0 = (s0 >> 4) & 3, mr0 = s0 & 15;
    int g1 = s1 >> 6, kc1 = (s1 >> 4) & 3, mr1 = s1 & 15;
    int arow0 = min(row0 + g0 * 16 + mr0, M - 1);   // clamp; extra rows dropped at store
    int arow1 = min(row0 + g1 * 16 + mr1, M - 1);
    const ushort* gA0 = &A[(size_t)arow0 * K + kc0 * 8];
    const ushort* gA1 = &A[(size_t)arow1 * K + kc1 * 8];
    const ushort* gB0 = &Bt[(size_t)(col0 + g0 * 16 + mr0) * K + kc0 * 8];  // N%128==0
    const ushort* gB1 = &Bt[(size_t)(col0 + g1 * 16 + mr1) * K + kc1 * 8];

    f32x4 acc[4][4];
    #pragma unroll
    for (int mt = 0; mt < 4; mt++)
        #pragma unroll
        for (int nt = 0; nt < 4; nt++)
            acc[mt][nt] = (f32x4){0.f, 0.f, 0.f, 0.f};

    // prologue: stage chunk 0 into buffer 0
    {
        bf16x8 a0 = *(const bf16x8*)gA0;
        bf16x8 a1 = *(const bf16x8*)gA1;
        bf16x8 b0 = *(const bf16x8*)gB0;
        bf16x8 b1 = *(const bf16x8*)gB1;
        *(bf16x8*)&As[0][s0 * 8] = a0;
        *(bf16x8*)&As[0][s1 * 8] = a1;
        *(bf16x8*)&Bs[0][s0 * 8] = b0;
        *(bf16x8*)&Bs[0][s1 * 8] = b1;
    }

    const int NC = K >> 5;
    for (int c = 0; c < NC; c++) {
        __syncthreads();
        int cur = c & 1, nxt = cur ^ 1;
        bf16x8 a0, a1, b0, b1;
        bool more = (c + 1 < NC);
        if (more) {
            gA0 += 32; gA1 += 32; gB0 += 32; gB1 += 32;
            a0 = *(const bf16x8*)gA0;
            a1 = *(const bf16x8*)gA1;
            b0 = *(const bf16x8*)gB0;
            b1 = *(const bf16x8*)gB1;
        }

        bf16x8 af[4], bfr[4];
        #pragma unroll
        for (int mt = 0; mt < 4; mt++)
            af[mt] = *(const bf16x8*)&As[cur][(size_t)(((wm * 4 + mt) * 64) + lane) * 8];
        #pragma unroll
        for (int nt = 0; nt < 4; nt++)
            bfr[nt] = *(const bf16x8*)&Bs[cur][(size_t)(((wn * 4 + nt) * 64) + lane) * 8];
        #pragma unroll
        for (int mt = 0; mt < 4; mt++)
            #pragma unroll
            for (int nt = 0; nt < 4; nt++)
                acc[mt][nt] = __builtin_amdgcn_mfma_f32_16x16x32_bf16(
                    bfr[nt], af[mt], acc[mt][nt], 0, 0, 0);   // swapped: D = C^T tile

        if (more) {
            *(bf16x8*)&As[nxt][s0 * 8] = a0;
            *(bf16x8*)&As[nxt][s1 * 8] = a1;
            *(bf16x8*)&Bs[nxt][s0 * 8] = b0;
            *(bf16x8*)&Bs[nxt][s1 * 8] = b1;
        }
    }

    // epilogue: lane holds C[row = lane&15][cols q*4..q*4+3] per tile
    int q = lane >> 4, cm = lane & 15;
    #pragma unroll
    for (int mt = 0; mt < 4; mt++) {
        int gr = row0 + wm * 64 + mt * 16 + cm;
        if (gr < M) {
            #pragma unroll
            for (int nt = 0; nt < 4; nt++) {
                int gc = col0 + wn * 64 + nt * 16 + q * 4;
                uint2 o;
                o.x = pack2bf(acc[mt][nt][0], acc[mt][nt][1]);
                o.y = pack2bf(acc[mt][nt][2], acc[mt][nt][3]);
                *(uint2*)&C[(size_t)gr * N + gc] = o;
            }
        }
    }
}

// ---------- gather1: max over in-edges + root + bias -> LN -> ReLU -> h (bf16) ----------
__global__ __launch_bounds__(256) void gather1(
    const ushort* __restrict__ xw1, const int* __restrict__ offs, const int* __restrict__ ep1,
    const float* __restrict__ bias, const float* __restrict__ g, const float* __restrict__ b,
    ushort* __restrict__ h)
{
    int n = blockIdx.x * 4 + (threadIdx.x >> 6);
    if (n >= NN) return;
    int lane = threadIdx.x & 63;
    int lane4 = lane * 4;
    int e0 = __builtin_amdgcn_readfirstlane(offs[n]);
    int e1 = __builtin_amdgcn_readfirstlane(offs[n + 1]);

    float m0 = -INFINITY, m1 = -INFINITY, m2 = -INFINITY, m3 = -INFINITY;
    int e = e0;
    for (; e + 8 <= e1; e += 8) {
        int p[8];
        #pragma unroll
        for (int j = 0; j < 8; j++) p[j] = ep1[e + j];
        ushort4 v[8];
        #pragma unroll
        for (int j = 0; j < 8; j++) v[j] = *(const ushort4*)&xw1[(size_t)(p[j] + lane4)];
        #pragma unroll
        for (int j = 0; j < 8; j++) {
            m0 = fmaxf(m0, b2f(v[j].x)); m1 = fmaxf(m1, b2f(v[j].y));
            m2 = fmaxf(m2, b2f(v[j].z)); m3 = fmaxf(m3, b2f(v[j].w));
        }
    }
    for (; e + 2 <= e1; e += 2) {
        int pa = ep1[e], pb = ep1[e + 1];
        ushort4 va = *(const ushort4*)&xw1[(size_t)(pa + lane4)];
        ushort4 vb = *(const ushort4*)&xw1[(size_t)(pb + lane4)];
        m0 = fmaxf(m0, fmaxf(b2f(va.x), b2f(vb.x)));
        m1 = fmaxf(m1, fmaxf(b2f(va.y), b2f(vb.y)));
        m2 = fmaxf(m2, fmaxf(b2f(va.z), b2f(vb.z)));
        m3 = fmaxf(m3, fmaxf(b2f(va.w), b2f(vb.w)));
    }
    for (; e < e1; e++) {
        int p = ep1[e];
        ushort4 v = *(const ushort4*)&xw1[(size_t)(p + lane4)];
        m0 = fmaxf(m0, b2f(v.x)); m1 = fmaxf(m1, b2f(v.y));
        m2 = fmaxf(m2, b2f(v.z)); m3 = fmaxf(m3, b2f(v.w));
    }
    if (e1 == e0) { m0 = m1 = m2 = m3 = 0.f; }

    ushort4 rt = *(const ushort4*)&xw1[(size_t)n * N1 + NREL * D_HID + lane4];
    int c = lane4;
    float t0 = m0 + b2f(rt.x) + bias[c + 0];
    float t1 = m1 + b2f(rt.y) + bias[c + 1];
    float t2 = m2 + b2f(rt.z) + bias[c + 2];
    float t3 = m3 + b2f(rt.w) + bias[c + 3];

    float s = t0 + t1 + t2 + t3;
    float s2 = t0 * t0 + t1 * t1 + t2 * t2 + t3 * t3;
    #pragma unroll
    for (int m = 32; m >= 1; m >>= 1) {
        s  += __shfl_xor(s,  m, 64);
        s2 += __shfl_xor(s2, m, 64);
    }
    float mu = s * (1.f / D_HID);
    float var = s2 * (1.f / D_HID) - mu * mu;
    float rs = rsqrtf(var + LN_EPS);

    ushort4 o;
    o.x = f2b(fmaxf((t0 - mu) * rs * g[c + 0] + b[c + 0], 0.f));
    o.y = f2b(fmaxf((t1 - mu) * rs * g[c + 1] + b[c + 1], 0.f));
    o.z = f2b(fmaxf((t2 - mu) * rs * g[c + 2] + b[c + 2], 0.f));
    o.w = f2b(fmaxf((t3 - mu) * rs * g[c + 3] + b[c + 3], 0.f));
    *(ushort4*)&h[(size_t)n * D_HID + c] = o;
}

// ---------- gather2: sum over in-edges + root + bias -> LN -> log_softmax -> out ----------
__global__ __launch_bounds__(256) void gather2(
    const ushort* __restrict__ xw2, const int* __restrict__ offs, const int* __restrict__ ep2,
    const float* __restrict__ bias, const float* __restrict__ g, const float* __restrict__ b,
    float* __restrict__ out)
{
    int n = blockIdx.x * 4 + (threadIdx.x >> 6);
    if (n >= NN) return;
    int lane = threadIdx.x & 63;
    int e0 = __builtin_amdgcn_readfirstlane(offs[n]);
    int e1 = __builtin_amdgcn_readfirstlane(offs[n + 1]);

    float s = 0.f;
    int e = e0;
    for (; e + 4 <= e1; e += 4) {
        int p0 = ep2[e + 0], p1 = ep2[e + 1], p2 = ep2[e + 2], p3 = ep2[e + 3];
        float a0 = b2f(xw2[(size_t)(p0 + lane)]);
        float a1 = b2f(xw2[(size_t)(p1 + lane)]);
        float a2 = b2f(xw2[(size_t)(p2 + lane)]);
        float a3 = b2f(xw2[(size_t)(p3 + lane)]);
        s += (a0 + a1) + (a2 + a3);
    }
    for (; e < e1; e++) {
        s += b2f(xw2[(size_t)(ep2[e] + lane)]);
    }
    float v = s + b2f(xw2[(size_t)n * N2 + NREL * D_OUT + lane]) + bias[lane];

    float sm = v, s2 = v * v;
    #pragma unroll
    for (int m = 32; m >= 1; m >>= 1) {
        sm += __shfl_xor(sm, m, 64);
        s2 += __shfl_xor(s2, m, 64);
    }
    float mu = sm * (1.f / D_OUT);
    float var = s2 * (1.f / D_OUT) - mu * mu;
    float y = (v - mu) * rsqrtf(var + LN_EPS) * g[lane] + b[lane];

    float mx = y;
    #pragma unroll
    for (int m = 32; m >= 1; m >>= 1) mx = fmaxf(mx, __shfl_xor(mx, m, 64));
    float ex = __expf(y - mx);
    float se = ex;
    #pragma unroll
    for (int m = 32; m >= 1; m >>= 1) se += __shfl_xor(se, m, 64);
    out[(size_t)n * D_OUT + lane] = y - mx - logf(se);
}

extern "C" void kernel_launch(void* const* d_in, const int* in_sizes, int n_in,
                              void* d_out, int out_size, void* d_ws, size_t ws_size,
                              hipStream_t stream)
{
    const float* x      = (const float*)d_in[0];
    const int*   eidx   = (const int*)  d_in[1];
    const int*   etype  = (const int*)  d_in[2];
    const float* bases1 = (const float*)d_in[3];
    const float* comp1  = (const float*)d_in[4];
    const float* root1  = (const float*)d_in[5];
    const float* bias1  = (const float*)d_in[6];
    const float* g1     = (const float*)d_in[7];
    const float* b1     = (const float*)d_in[8];
    const float* bases2 = (const float*)d_in[9];
    const float* comp2  = (const float*)d_in[10];
    const float* root2  = (const float*)d_in[11];
    const float* bias2  = (const float*)d_in[12];
    const float* g2     = (const float*)d_in[13];
    const float* b2     = (const float*)d_in[14];

    const int* src = eidx;
    const int* dst = eidx + NE;

    char* p = (char*)d_ws;
    auto alloc = [&](size_t bytes) -> char* {
        char* r = p;
        p += (bytes + 255) & ~(size_t)255;
        return r;
    };
    ushort* xbf    = (ushort*)alloc((size_t)NN * D_IN * 2);
    ushort* w1t    = (ushort*)alloc((size_t)N1 * D_IN * 2);
    ushort* w2t    = (ushort*)alloc((size_t)N2 * D_HID * 2);
    ushort* xw1    = (ushort*)alloc((size_t)NN * N1 * 2);
    ushort* xw2    = (ushort*)alloc((size_t)NN * N2 * 2);
    ushort* h      = (ushort*)alloc((size_t)NN * D_HID * 2);
    int*    deg    = (int*)   alloc((size_t)NN * 4);
    int*    local  = (int*)   alloc((size_t)NN * 4);
    int*    bsum   = (int*)   alloc((size_t)NBLK * 4);
    int*    offs   = (int*)   alloc((size_t)(NN + 1) * 4);
    int*    cursor = (int*)   alloc((size_t)NN * 4);
    int*    ep1    = (int*)   alloc((size_t)NE * 4);
    int*    ep2    = (int*)   alloc((size_t)NE * 4);

    const int SZP = N1 * D_IN + N2 * D_HID + NN * D_IN;
    prep_all<<<(SZP + 255) / 256, 256, 0, stream>>>(
        bases1, comp1, root1, bases2, comp2, root2, x, w1t, w2t, xbf);

    hipMemsetAsync(deg, 0, (size_t)NN * 4, stream);
    hist_dst<<<(NE + 255) / 256, 256, 0, stream>>>(dst, deg);
    scan_blk<<<NBLK, 256, 0, stream>>>(deg, local, bsum);
    scan_fin<<<NBLK, 256, 0, stream>>>(local, bsum, offs, cursor);
    scatter_ep<<<(NE + 255) / 256, 256, 0, stream>>>(src, dst, etype, cursor, ep1, ep2);

    gemm_bf16<<<dim3(N1 / 128, (NN + 127) / 128), 256, 0, stream>>>(xbf, w1t, xw1, NN, N1, D_IN);
    gather1<<<(NN + 3) / 4, 256, 0, stream>>>(xw1, offs, ep1, bias1, g1, b1, h);

    gemm_bf16<<<dim3(N2 / 128, (NN + 127) / 128), 256, 0, stream>>>(h, w2t, xw2, NN, N2, D_HID);
    gather2<<<(NN + 3) / 4, 256, 0, stream>>>(xw2, offs, ep2, bias2, g2, b2, (float*)d_out);
}

// Round 9
// 251.192 us; speedup vs baseline: 1.0681x; 1.0681x over previous
//
#include <hip/hip_runtime.h>
#include <math.h>

#define NN 20000
#define NE 320000
#define NREL 9
#define NBASES 9
#define D_IN 128
#define D_HID 256
#define D_OUT 64
#define LN_EPS 1e-5f

#define N1 (NREL * D_HID + D_HID)   // 2560
#define N2 (NREL * D_OUT + D_OUT)   // 640
#define NBLK ((NN + 255) / 256)     // 79

typedef __attribute__((ext_vector_type(8))) short bf16x8;
typedef __attribute__((ext_vector_type(4))) float f32x4;

__device__ inline ushort f2b(float f) {
    unsigned u = __float_as_uint(f);
    return (ushort)((u + 0x7FFFu + ((u >> 16) & 1u)) >> 16);
}
__device__ inline float b2f(ushort h) { return __uint_as_float(((unsigned)h) << 16); }
__device__ inline unsigned pack2bf(float f0, float f1) {
    return (unsigned)f2b(f0) | ((unsigned)f2b(f1) << 16);
}

// ---------- fused prep: weights + x cast + dst histogram (one launch) ----------
__global__ __launch_bounds__(256) void prep_all(
    const float* __restrict__ bases1, const float* __restrict__ comp1, const float* __restrict__ root1,
    const float* __restrict__ bases2, const float* __restrict__ comp2, const float* __restrict__ root2,
    const float* __restrict__ x, const int* __restrict__ dst,
    ushort* __restrict__ w1t, ushort* __restrict__ w2t, ushort* __restrict__ xbf,
    int* __restrict__ deg)
{
    const int SZ1 = N1 * D_IN;
    const int SZ2 = N2 * D_HID;
    const int SZX = NN * D_IN;
    int tid = blockIdx.x * 256 + threadIdx.x;
    if (tid < SZ1) {
        int n = tid >> 7, k = tid & 127;
        float s;
        if (n < NREL * D_HID) {
            int r = n >> 8, o = n & 255;
            s = 0.f;
            #pragma unroll
            for (int b = 0; b < NBASES; b++)
                s += comp1[r * NBASES + b] * bases1[(b * D_IN + k) * D_HID + o];
        } else {
            s = root1[k * D_HID + (n - NREL * D_HID)];
        }
        w1t[tid] = f2b(s);
    } else if (tid < SZ1 + SZ2) {
        int j = tid - SZ1;
        int n = j >> 8, k = j & 255;
        float s;
        if (n < NREL * D_OUT) {
            int r = n >> 6, o = n & 63;
            s = 0.f;
            #pragma unroll
            for (int b = 0; b < NBASES; b++)
                s += comp2[r * NBASES + b] * bases2[(b * D_HID + k) * D_OUT + o];
        } else {
            s = root2[k * D_OUT + (n - NREL * D_OUT)];
        }
        w2t[j] = f2b(s);
    } else if (tid < SZ1 + SZ2 + SZX) {
        int j = tid - SZ1 - SZ2;
        xbf[j] = f2b(x[j]);
    } else if (tid < SZ1 + SZ2 + SZX + NE) {
        int e = tid - SZ1 - SZ2 - SZX;
        atomicAdd(&deg[dst[e]], 1);
    }
}

// ---------- CSR build ----------
__global__ __launch_bounds__(256) void scan_blk(
    const int* __restrict__ deg, int* __restrict__ local, int* __restrict__ bsum)
{
    __shared__ int wsum[4];
    int tid = threadIdx.x, lane = tid & 63, w = tid >> 6;
    int i = blockIdx.x * 256 + tid;
    int v = (i < NN) ? deg[i] : 0;
    int x = v;
    #pragma unroll
    for (int d = 1; d < 64; d <<= 1) {
        int y = __shfl_up(x, d, 64);
        if (lane >= d) x += y;
    }
    if (lane == 63) wsum[w] = x;
    __syncthreads();
    int woff = 0;
    for (int j = 0; j < w; j++) woff += wsum[j];
    if (i < NN) local[i] = woff + x - v;
    if (tid == 255) bsum[blockIdx.x] = woff + x;
}

// each block redundantly top-scans the 79 block sums, then finalizes
__global__ __launch_bounds__(256) void scan_fin(
    const int* __restrict__ local, const int* __restrict__ bsum,
    int* __restrict__ offs, int* __restrict__ cursor)
{
    __shared__ int boff_s[NBLK];
    int tid = threadIdx.x;
    if (tid < 64) {
        int carry = 0;
        for (int base = 0; base < NBLK; base += 64) {
            int i = base + tid;
            int v = (i < NBLK) ? bsum[i] : 0;
            int x = v;
            #pragma unroll
            for (int d = 1; d < 64; d <<= 1) {
                int y = __shfl_up(x, d, 64);
                if (tid >= d) x += y;
            }
            if (i < NBLK) boff_s[i] = carry + x - v;
            carry += __shfl(x, 63, 64);
        }
    }
    __syncthreads();
    int i = blockIdx.x * 256 + tid;
    if (i < NN) {
        int o = local[i] + boff_s[i >> 8];
        offs[i] = o;
        cursor[i] = o;
    }
    if (i == NN) offs[NN] = NE;
}

// ep1 = src*N1 + rel*D_HID; note ep2 == ep1>>2 exactly, so no ep2 array.
__global__ __launch_bounds__(256) void scatter_ep(
    const int* __restrict__ src, const int* __restrict__ dst, const int* __restrict__ etype,
    int* __restrict__ cursor, int* __restrict__ ep1)
{
    int e = blockIdx.x * 256 + threadIdx.x;
    if (e >= NE) return;
    int d = dst[e];
    int s = src[e], r = etype[e];
    int pos = atomicAdd(&cursor[d], 1);
    ep1[pos] = s * N1 + r * D_HID;
}

// ---------- bf16 MFMA GEMM: C[M][N] = A[M][K] @ Bt[N][K]^T ----------
// 128x128 tile, BK=32, double-buffered LDS, VGPR staging (chunk c+1 loads
// overlap chunk c MFMA). Global loads coalesced (thread t -> row t>>2,
// chunk q=t&3: 4 lanes = 64 B per row). LDS swizzle: within each 16-row
// tile, chunk (mr,q) lives at slot q*16 + ((mr + 2q) & 15), 16 B/slot.
// Writer 8-lane phases hit bank-quads {0,2,4,6,1,3,5,7} (distinct) and
// reader phases (kq=l>>4, mr=l&15) read consecutive slots -> both sides
// conflict-free, no padding. Operand-swapped MFMA -> C^T tiles -> uint2.
__global__ __launch_bounds__(256) void gemm_bf16(
    const ushort* __restrict__ A, const ushort* __restrict__ Bt, ushort* __restrict__ C,
    int M, int N, int K)
{
    __shared__ ushort As[2][512 * 8];   // 8 KB per buffer
    __shared__ ushort Bs[2][512 * 8];   // 32 KB total

    int tid = threadIdx.x;
    int lane = tid & 63, w = tid >> 6;
    int wm = w >> 1, wn = w & 1;
    int row0 = blockIdx.y * 128, col0 = blockIdx.x * 128;

    // writer: thread t covers rows r0 and r0+64 at k-chunk q0
    int r0 = tid >> 2, q0 = tid & 3;
    int mrw = r0 & 15, gw = r0 >> 4;
    int sw = q0 * 16 + ((mrw + 2 * q0) & 15);          // swizzled within-tile slot
    int lo0 = (gw * 64 + sw) * 8;
    int lo1 = ((gw + 4) * 64 + sw) * 8;
    int arow0 = min(row0 + r0, M - 1);                  // clamp; dropped at store
    int arow1 = min(row0 + r0 + 64, M - 1);
    const ushort* gA0 = &A[(size_t)arow0 * K + q0 * 8];
    const ushort* gA1 = &A[(size_t)arow1 * K + q0 * 8];
    const ushort* gB0 = &Bt[(size_t)(col0 + r0) * K + q0 * 8];        // N%128==0
    const ushort* gB1 = &Bt[(size_t)(col0 + r0 + 64) * K + q0 * 8];

    // reader: lane l needs (row mr, chunk kq) -> slot kq*16 + ((mr+2kq)&15)
    int mr = lane & 15, kq = lane >> 4;
    int inner = (kq * 16 + ((mr + 2 * kq) & 15)) * 8;

    f32x4 acc[4][4];
    #pragma unroll
    for (int mt = 0; mt < 4; mt++)
        #pragma unroll
        for (int nt = 0; nt < 4; nt++)
            acc[mt][nt] = (f32x4){0.f, 0.f, 0.f, 0.f};

    // prologue: stage chunk 0 into buffer 0
    {
        bf16x8 a0 = *(const bf16x8*)gA0;
        bf16x8 a1 = *(const bf16x8*)gA1;
        bf16x8 b0 = *(const bf16x8*)gB0;
        bf16x8 b1 = *(const bf16x8*)gB1;
        *(bf16x8*)&As[0][lo0] = a0;
        *(bf16x8*)&As[0][lo1] = a1;
        *(bf16x8*)&Bs[0][lo0] = b0;
        *(bf16x8*)&Bs[0][lo1] = b1;
    }

    const int NC = K >> 5;
    for (int c = 0; c < NC; c++) {
        __syncthreads();
        int cur = c & 1, nxt = cur ^ 1;
        bf16x8 a0, a1, b0, b1;
        bool more = (c + 1 < NC);
        if (more) {
            gA0 += 32; gA1 += 32; gB0 += 32; gB1 += 32;
            a0 = *(const bf16x8*)gA0;
            a1 = *(const bf16x8*)gA1;
            b0 = *(const bf16x8*)gB0;
            b1 = *(const bf16x8*)gB1;
        }

        bf16x8 af[4], bfr[4];
        #pragma unroll
        for (int mt = 0; mt < 4; mt++)
            af[mt] = *(const bf16x8*)&As[cur][(size_t)((wm * 4 + mt) * 64) * 8 + inner];
        #pragma unroll
        for (int nt = 0; nt < 4; nt++)
            bfr[nt] = *(const bf16x8*)&Bs[cur][(size_t)((wn * 4 + nt) * 64) * 8 + inner];
        #pragma unroll
        for (int mt = 0; mt < 4; mt++)
            #pragma unroll
            for (int nt = 0; nt < 4; nt++)
                acc[mt][nt] = __builtin_amdgcn_mfma_f32_16x16x32_bf16(
                    bfr[nt], af[mt], acc[mt][nt], 0, 0, 0);   // swapped: D = C^T tile

        if (more) {
            *(bf16x8*)&As[nxt][lo0] = a0;
            *(bf16x8*)&As[nxt][lo1] = a1;
            *(bf16x8*)&Bs[nxt][lo0] = b0;
            *(bf16x8*)&Bs[nxt][lo1] = b1;
        }
    }

    // epilogue: lane holds C[row = lane&15][cols q*4..q*4+3] per tile
    int q = lane >> 4, cm = lane & 15;
    #pragma unroll
    for (int mt = 0; mt < 4; mt++) {
        int gr = row0 + wm * 64 + mt * 16 + cm;
        if (gr < M) {
            #pragma unroll
            for (int nt = 0; nt < 4; nt++) {
                int gc = col0 + wn * 64 + nt * 16 + q * 4;
                uint2 o;
                o.x = pack2bf(acc[mt][nt][0], acc[mt][nt][1]);
                o.y = pack2bf(acc[mt][nt][2], acc[mt][nt][3]);
                *(uint2*)&C[(size_t)gr * N + gc] = o;
            }
        }
    }
}

// ---------- gather1: max over in-edges + root + bias -> LN -> ReLU -> h (bf16) ----------
__global__ __launch_bounds__(256) void gather1(
    const ushort* __restrict__ xw1, const int* __restrict__ offs, const int* __restrict__ ep1,
    const float* __restrict__ bias, const float* __restrict__ g, const float* __restrict__ b,
    ushort* __restrict__ h)
{
    int n = blockIdx.x * 4 + (threadIdx.x >> 6);
    if (n >= NN) return;
    int lane = threadIdx.x & 63;
    int lane4 = lane * 4;
    int e0 = __builtin_amdgcn_readfirstlane(offs[n]);
    int e1 = __builtin_amdgcn_readfirstlane(offs[n + 1]);

    float m0 = -INFINITY, m1 = -INFINITY, m2 = -INFINITY, m3 = -INFINITY;
    int e = e0;
    for (; e + 8 <= e1; e += 8) {
        int p[8];
        #pragma unroll
        for (int j = 0; j < 8; j++) p[j] = ep1[e + j];
        ushort4 v[8];
        #pragma unroll
        for (int j = 0; j < 8; j++) v[j] = *(const ushort4*)&xw1[(size_t)(p[j] + lane4)];
        #pragma unroll
        for (int j = 0; j < 8; j++) {
            m0 = fmaxf(m0, b2f(v[j].x)); m1 = fmaxf(m1, b2f(v[j].y));
            m2 = fmaxf(m2, b2f(v[j].z)); m3 = fmaxf(m3, b2f(v[j].w));
        }
    }
    for (; e + 2 <= e1; e += 2) {
        int pa = ep1[e], pb = ep1[e + 1];
        ushort4 va = *(const ushort4*)&xw1[(size_t)(pa + lane4)];
        ushort4 vb = *(const ushort4*)&xw1[(size_t)(pb + lane4)];
        m0 = fmaxf(m0, fmaxf(b2f(va.x), b2f(vb.x)));
        m1 = fmaxf(m1, fmaxf(b2f(va.y), b2f(vb.y)));
        m2 = fmaxf(m2, fmaxf(b2f(va.z), b2f(vb.z)));
        m3 = fmaxf(m3, fmaxf(b2f(va.w), b2f(vb.w)));
    }
    for (; e < e1; e++) {
        int p = ep1[e];
        ushort4 v = *(const ushort4*)&xw1[(size_t)(p + lane4)];
        m0 = fmaxf(m0, b2f(v.x)); m1 = fmaxf(m1, b2f(v.y));
        m2 = fmaxf(m2, b2f(v.z)); m3 = fmaxf(m3, b2f(v.w));
    }
    if (e1 == e0) { m0 = m1 = m2 = m3 = 0.f; }

    ushort4 rt = *(const ushort4*)&xw1[(size_t)n * N1 + NREL * D_HID + lane4];
    int c = lane4;
    float t0 = m0 + b2f(rt.x) + bias[c + 0];
    float t1 = m1 + b2f(rt.y) + bias[c + 1];
    float t2 = m2 + b2f(rt.z) + bias[c + 2];
    float t3 = m3 + b2f(rt.w) + bias[c + 3];

    float s = t0 + t1 + t2 + t3;
    float s2 = t0 * t0 + t1 * t1 + t2 * t2 + t3 * t3;
    #pragma unroll
    for (int m = 32; m >= 1; m >>= 1) {
        s  += __shfl_xor(s,  m, 64);
        s2 += __shfl_xor(s2, m, 64);
    }
    float mu = s * (1.f / D_HID);
    float var = s2 * (1.f / D_HID) - mu * mu;
    float rs = rsqrtf(var + LN_EPS);

    ushort4 o;
    o.x = f2b(fmaxf((t0 - mu) * rs * g[c + 0] + b[c + 0], 0.f));
    o.y = f2b(fmaxf((t1 - mu) * rs * g[c + 1] + b[c + 1], 0.f));
    o.z = f2b(fmaxf((t2 - mu) * rs * g[c + 2] + b[c + 2], 0.f));
    o.w = f2b(fmaxf((t3 - mu) * rs * g[c + 3] + b[c + 3], 0.f));
    *(ushort4*)&h[(size_t)n * D_HID + c] = o;
}

// ---------- gather2: sum over in-edges + root + bias -> LN -> log_softmax -> out ----------
__global__ __launch_bounds__(256) void gather2(
    const ushort* __restrict__ xw2, const int* __restrict__ offs, const int* __restrict__ ep1,
    const float* __restrict__ bias, const float* __restrict__ g, const float* __restrict__ b,
    float* __restrict__ out)
{
    int n = blockIdx.x * 4 + (threadIdx.x >> 6);
    if (n >= NN) return;
    int lane = threadIdx.x & 63;
    int e0 = __builtin_amdgcn_readfirstlane(offs[n]);
    int e1 = __builtin_amdgcn_readfirstlane(offs[n + 1]);

    float s = 0.f;
    int e = e0;
    for (; e + 4 <= e1; e += 4) {
        int p0 = ep1[e + 0] >> 2, p1 = ep1[e + 1] >> 2;
        int p2 = ep1[e + 2] >> 2, p3 = ep1[e + 3] >> 2;
        float a0 = b2f(xw2[(size_t)(p0 + lane)]);
        float a1 = b2f(xw2[(size_t)(p1 + lane)]);
        float a2 = b2f(xw2[(size_t)(p2 + lane)]);
        float a3 = b2f(xw2[(size_t)(p3 + lane)]);
        s += (a0 + a1) + (a2 + a3);
    }
    for (; e < e1; e++) {
        s += b2f(xw2[(size_t)((ep1[e] >> 2) + lane)]);
    }
    float v = s + b2f(xw2[(size_t)n * N2 + NREL * D_OUT + lane]) + bias[lane];

    float sm = v, s2 = v * v;
    #pragma unroll
    for (int m = 32; m >= 1; m >>= 1) {
        sm += __shfl_xor(sm, m, 64);
        s2 += __shfl_xor(s2, m, 64);
    }
    float mu = sm * (1.f / D_OUT);
    float var = s2 * (1.f / D_OUT) - mu * mu;
    float y = (v - mu) * rsqrtf(var + LN_EPS) * g[lane] + b[lane];

    float mx = y;
    #pragma unroll
    for (int m = 32; m >= 1; m >>= 1) mx = fmaxf(mx, __shfl_xor(mx, m, 64));
    float ex = __expf(y - mx);
    float se = ex;
    #pragma unroll
    for (int m = 32; m >= 1; m >>= 1) se += __shfl_xor(se, m, 64);
    out[(size_t)n * D_OUT + lane] = y - mx - logf(se);
}

extern "C" void kernel_launch(void* const* d_in, const int* in_sizes, int n_in,
                              void* d_out, int out_size, void* d_ws, size_t ws_size,
                              hipStream_t stream)
{
    const float* x      = (const float*)d_in[0];
    const int*   eidx   = (const int*)  d_in[1];
    const int*   etype  = (const int*)  d_in[2];
    const float* bases1 = (const float*)d_in[3];
    const float* comp1  = (const float*)d_in[4];
    const float* root1  = (const float*)d_in[5];
    const float* bias1  = (const float*)d_in[6];
    const float* g1     = (const float*)d_in[7];
    const float* b1     = (const float*)d_in[8];
    const float* bases2 = (const float*)d_in[9];
    const float* comp2  = (const float*)d_in[10];
    const float* root2  = (const float*)d_in[11];
    const float* bias2  = (const float*)d_in[12];
    const float* g2     = (const float*)d_in[13];
    const float* b2     = (const float*)d_in[14];

    const int* src = eidx;
    const int* dst = eidx + NE;

    char* p = (char*)d_ws;
    auto alloc = [&](size_t bytes) -> char* {
        char* r = p;
        p += (bytes + 255) & ~(size_t)255;
        return r;
    };
    ushort* xbf    = (ushort*)alloc((size_t)NN * D_IN * 2);
    ushort* w1t    = (ushort*)alloc((size_t)N1 * D_IN * 2);
    ushort* w2t    = (ushort*)alloc((size_t)N2 * D_HID * 2);
    ushort* xw1    = (ushort*)alloc((size_t)NN * N1 * 2);
    ushort* xw2    = (ushort*)alloc((size_t)NN * N2 * 2);
    ushort* h      = (ushort*)alloc((size_t)NN * D_HID * 2);
    int*    deg    = (int*)   alloc((size_t)NN * 4);
    int*    local  = (int*)   alloc((size_t)NN * 4);
    int*    bsum   = (int*)   alloc((size_t)NBLK * 4);
    int*    offs   = (int*)   alloc((size_t)(NN + 1) * 4);
    int*    cursor = (int*)   alloc((size_t)NN * 4);
    int*    ep1    = (int*)   alloc((size_t)NE * 4);

    hipMemsetAsync(deg, 0, (size_t)NN * 4, stream);
    const int SZP = N1 * D_IN + N2 * D_HID + NN * D_IN + NE;
    prep_all<<<(SZP + 255) / 256, 256, 0, stream>>>(
        bases1, comp1, root1, bases2, comp2, root2, x, dst, w1t, w2t, xbf, deg);

    scan_blk<<<NBLK, 256, 0, stream>>>(deg, local, bsum);
    scan_fin<<<NBLK, 256, 0, stream>>>(local, bsum, offs, cursor);
    scatter_ep<<<(NE + 255) / 256, 256, 0, stream>>>(src, dst, etype, cursor, ep1);

    gemm_bf16<<<dim3(N1 / 128, (NN + 127) / 128), 256, 0, stream>>>(xbf, w1t, xw1, NN, N1, D_IN);
    gather1<<<(NN + 3) / 4, 256, 0, stream>>>(xw1, offs, ep1, bias1, g1, b1, h);

    gemm_bf16<<<dim3(N2 / 128, (NN + 127) / 128), 256, 0, stream>>>(h, w2t, xw2, NN, N2, D_HID);
    gather2<<<(NN + 3) / 4, 256, 0, stream>>>(xw2, offs, ep1, bias2, g2, b2, (float*)d_out);
}

// Round 10
// 241.025 us; speedup vs baseline: 1.1131x; 1.0422x over previous
//
#include <hip/hip_runtime.h>
#include <math.h>

#define NN 20000
#define NE 320000
#define NREL 9
#define NBASES 9
#define D_IN 128
#define D_HID 256
#define D_OUT 64
#define LN_EPS 1e-5f

#define N1 (NREL * D_HID + D_HID)   // 2560
#define N2 (NREL * D_OUT + D_OUT)   // 640
#define NBLK ((NN + 255) / 256)     // 79

typedef __attribute__((ext_vector_type(8))) short bf16x8;
typedef __attribute__((ext_vector_type(4))) float f32x4;

__device__ inline ushort f2b(float f) {
    unsigned u = __float_as_uint(f);
    return (ushort)((u + 0x7FFFu + ((u >> 16) & 1u)) >> 16);
}
__device__ inline float b2f(ushort h) { return __uint_as_float(((unsigned)h) << 16); }
__device__ inline unsigned pack2bf(float f0, float f1) {
    return (unsigned)f2b(f0) | ((unsigned)f2b(f1) << 16);
}

// ---------- fused prep: weights (coalesced basis reads) + x cast + dst histogram ----------
// w1 section: thread -> (k, o) with o lane-minor; reads bases1[b][k][o] coalesced,
// computes all 9 relations at once (scattered 2B writes merge in L2).
__global__ __launch_bounds__(256) void prep_all(
    const float* __restrict__ bases1, const float* __restrict__ comp1, const float* __restrict__ root1,
    const float* __restrict__ bases2, const float* __restrict__ comp2, const float* __restrict__ root2,
    const float* __restrict__ x, const int* __restrict__ dst,
    ushort* __restrict__ w1t, ushort* __restrict__ w2t, ushort* __restrict__ xbf,
    int* __restrict__ deg)
{
    const int SZW1 = D_IN * D_HID;   // 32768
    const int SZW2 = D_HID * D_OUT;  // 16384
    const int SZX  = NN * D_IN;      // 2560000
    int tid = blockIdx.x * 256 + threadIdx.x;
    if (tid < SZW1) {
        int o = tid & (D_HID - 1), k = tid >> 8;          // o lane-minor
        float acc[NREL];
        #pragma unroll
        for (int r = 0; r < NREL; r++) acc[r] = 0.f;
        #pragma unroll
        for (int b = 0; b < NBASES; b++) {
            float bs = bases1[(b * D_IN + k) * D_HID + o];  // coalesced
            #pragma unroll
            for (int r = 0; r < NREL; r++) acc[r] += comp1[r * NBASES + b] * bs;
        }
        #pragma unroll
        for (int r = 0; r < NREL; r++)
            w1t[(r * D_HID + o) * D_IN + k] = f2b(acc[r]);
        w1t[(NREL * D_HID + o) * D_IN + k] = f2b(root1[k * D_HID + o]);  // coalesced read
    } else if (tid < SZW1 + SZW2) {
        int j = tid - SZW1;
        int o = j & (D_OUT - 1), k = j >> 6;
        float acc[NREL];
        #pragma unroll
        for (int r = 0; r < NREL; r++) acc[r] = 0.f;
        #pragma unroll
        for (int b = 0; b < NBASES; b++) {
            float bs = bases2[(b * D_HID + k) * D_OUT + o];  // coalesced
            #pragma unroll
            for (int r = 0; r < NREL; r++) acc[r] += comp2[r * NBASES + b] * bs;
        }
        #pragma unroll
        for (int r = 0; r < NREL; r++)
            w2t[(r * D_OUT + o) * D_HID + k] = f2b(acc[r]);
        w2t[(NREL * D_OUT + o) * D_HID + k] = f2b(root2[k * D_OUT + o]);
    } else if (tid < SZW1 + SZW2 + SZX) {
        int j = tid - SZW1 - SZW2;
        xbf[j] = f2b(x[j]);
    } else if (tid < SZW1 + SZW2 + SZX + NE) {
        int e = tid - SZW1 - SZW2 - SZX;
        atomicAdd(&deg[dst[e]], 1);
    }
}

// ---------- CSR build ----------
__global__ __launch_bounds__(256) void scan_blk(
    const int* __restrict__ deg, int* __restrict__ local, int* __restrict__ bsum)
{
    __shared__ int wsum[4];
    int tid = threadIdx.x, lane = tid & 63, w = tid >> 6;
    int i = blockIdx.x * 256 + tid;
    int v = (i < NN) ? deg[i] : 0;
    int x = v;
    #pragma unroll
    for (int d = 1; d < 64; d <<= 1) {
        int y = __shfl_up(x, d, 64);
        if (lane >= d) x += y;
    }
    if (lane == 63) wsum[w] = x;
    __syncthreads();
    int woff = 0;
    for (int j = 0; j < w; j++) woff += wsum[j];
    if (i < NN) local[i] = woff + x - v;
    if (tid == 255) bsum[blockIdx.x] = woff + x;
}

__global__ __launch_bounds__(256) void scan_fin(
    const int* __restrict__ local, const int* __restrict__ bsum,
    int* __restrict__ offs, int* __restrict__ cursor)
{
    __shared__ int boff_s[NBLK];
    int tid = threadIdx.x;
    if (tid < 64) {
        int carry = 0;
        for (int base = 0; base < NBLK; base += 64) {
            int i = base + tid;
            int v = (i < NBLK) ? bsum[i] : 0;
            int x = v;
            #pragma unroll
            for (int d = 1; d < 64; d <<= 1) {
                int y = __shfl_up(x, d, 64);
                if (tid >= d) x += y;
            }
            if (i < NBLK) boff_s[i] = carry + x - v;
            carry += __shfl(x, 63, 64);
        }
    }
    __syncthreads();
    int i = blockIdx.x * 256 + tid;
    if (i < NN) {
        int o = local[i] + boff_s[i >> 8];
        offs[i] = o;
        cursor[i] = o;
    }
    if (i == NN) offs[NN] = NE;
}

// ep1 = src*N1 + rel*D_HID; ep2 == ep1>>2 exactly, so no ep2 array.
__global__ __launch_bounds__(256) void scatter_ep(
    const int* __restrict__ src, const int* __restrict__ dst, const int* __restrict__ etype,
    int* __restrict__ cursor, int* __restrict__ ep1)
{
    int e = blockIdx.x * 256 + threadIdx.x;
    if (e >= NE) return;
    int d = dst[e];
    int s = src[e], r = etype[e];
    int pos = atomicAdd(&cursor[d], 1);
    ep1[pos] = s * N1 + r * D_HID;
}

// ---------- bf16 MFMA GEMM (r9 config, best measured): C = A @ Bt^T ----------
// 128x128 tile, BK=32, double-buffered LDS, VGPR staging, swizzled LDS slots
// (residual conflicts ~2-way = free), operand-swapped MFMA -> C^T tiles -> uint2.
__global__ __launch_bounds__(256) void gemm_bf16(
    const ushort* __restrict__ A, const ushort* __restrict__ Bt, ushort* __restrict__ C,
    int M, int N, int K)
{
    __shared__ ushort As[2][512 * 8];
    __shared__ ushort Bs[2][512 * 8];

    int tid = threadIdx.x;
    int lane = tid & 63, w = tid >> 6;
    int wm = w >> 1, wn = w & 1;
    int row0 = blockIdx.y * 128, col0 = blockIdx.x * 128;

    int r0 = tid >> 2, q0 = tid & 3;
    int mrw = r0 & 15, gw = r0 >> 4;
    int sw = q0 * 16 + ((mrw + 2 * q0) & 15);
    int lo0 = (gw * 64 + sw) * 8;
    int lo1 = ((gw + 4) * 64 + sw) * 8;
    int arow0 = min(row0 + r0, M - 1);
    int arow1 = min(row0 + r0 + 64, M - 1);
    const ushort* gA0 = &A[(size_t)arow0 * K + q0 * 8];
    const ushort* gA1 = &A[(size_t)arow1 * K + q0 * 8];
    const ushort* gB0 = &Bt[(size_t)(col0 + r0) * K + q0 * 8];
    const ushort* gB1 = &Bt[(size_t)(col0 + r0 + 64) * K + q0 * 8];

    int mr = lane & 15, kq = lane >> 4;
    int inner = (kq * 16 + ((mr + 2 * kq) & 15)) * 8;

    f32x4 acc[4][4];
    #pragma unroll
    for (int mt = 0; mt < 4; mt++)
        #pragma unroll
        for (int nt = 0; nt < 4; nt++)
            acc[mt][nt] = (f32x4){0.f, 0.f, 0.f, 0.f};

    {
        bf16x8 a0 = *(const bf16x8*)gA0;
        bf16x8 a1 = *(const bf16x8*)gA1;
        bf16x8 b0 = *(const bf16x8*)gB0;
        bf16x8 b1 = *(const bf16x8*)gB1;
        *(bf16x8*)&As[0][lo0] = a0;
        *(bf16x8*)&As[0][lo1] = a1;
        *(bf16x8*)&Bs[0][lo0] = b0;
        *(bf16x8*)&Bs[0][lo1] = b1;
    }

    const int NC = K >> 5;
    for (int c = 0; c < NC; c++) {
        __syncthreads();
        int cur = c & 1, nxt = cur ^ 1;
        bf16x8 a0, a1, b0, b1;
        bool more = (c + 1 < NC);
        if (more) {
            gA0 += 32; gA1 += 32; gB0 += 32; gB1 += 32;
            a0 = *(const bf16x8*)gA0;
            a1 = *(const bf16x8*)gA1;
            b0 = *(const bf16x8*)gB0;
            b1 = *(const bf16x8*)gB1;
        }

        bf16x8 af[4], bfr[4];
        #pragma unroll
        for (int mt = 0; mt < 4; mt++)
            af[mt] = *(const bf16x8*)&As[cur][(size_t)((wm * 4 + mt) * 64) * 8 + inner];
        #pragma unroll
        for (int nt = 0; nt < 4; nt++)
            bfr[nt] = *(const bf16x8*)&Bs[cur][(size_t)((wn * 4 + nt) * 64) * 8 + inner];
        #pragma unroll
        for (int mt = 0; mt < 4; mt++)
            #pragma unroll
            for (int nt = 0; nt < 4; nt++)
                acc[mt][nt] = __builtin_amdgcn_mfma_f32_16x16x32_bf16(
                    bfr[nt], af[mt], acc[mt][nt], 0, 0, 0);

        if (more) {
            *(bf16x8*)&As[nxt][lo0] = a0;
            *(bf16x8*)&As[nxt][lo1] = a1;
            *(bf16x8*)&Bs[nxt][lo0] = b0;
            *(bf16x8*)&Bs[nxt][lo1] = b1;
        }
    }

    int q = lane >> 4, cm = lane & 15;
    #pragma unroll
    for (int mt = 0; mt < 4; mt++) {
        int gr = row0 + wm * 64 + mt * 16 + cm;
        if (gr < M) {
            #pragma unroll
            for (int nt = 0; nt < 4; nt++) {
                int gc = col0 + wn * 64 + nt * 16 + q * 4;
                uint2 o;
                o.x = pack2bf(acc[mt][nt][0], acc[mt][nt][1]);
                o.y = pack2bf(acc[mt][nt][2], acc[mt][nt][3]);
                *(uint2*)&C[(size_t)gr * N + gc] = o;
            }
        }
    }
}

// ---------- gather1: max over in-edges + root + bias -> LN -> ReLU -> h (bf16) ----------
__global__ __launch_bounds__(256) void gather1(
    const ushort* __restrict__ xw1, const int* __restrict__ offs, const int* __restrict__ ep1,
    const float* __restrict__ bias, const float* __restrict__ g, const float* __restrict__ b,
    ushort* __restrict__ h)
{
    int n = blockIdx.x * 4 + (threadIdx.x >> 6);
    if (n >= NN) return;
    int lane = threadIdx.x & 63;
    int lane4 = lane * 4;
    int e0 = __builtin_amdgcn_readfirstlane(offs[n]);
    int e1 = __builtin_amdgcn_readfirstlane(offs[n + 1]);

    float m0 = -INFINITY, m1 = -INFINITY, m2 = -INFINITY, m3 = -INFINITY;
    int e = e0;
    for (; e + 8 <= e1; e += 8) {
        int p[8];
        #pragma unroll
        for (int j = 0; j < 8; j++) p[j] = ep1[e + j];
        ushort4 v[8];
        #pragma unroll
        for (int j = 0; j < 8; j++) v[j] = *(const ushort4*)&xw1[(size_t)(p[j] + lane4)];
        #pragma unroll
        for (int j = 0; j < 8; j++) {
            m0 = fmaxf(m0, b2f(v[j].x)); m1 = fmaxf(m1, b2f(v[j].y));
            m2 = fmaxf(m2, b2f(v[j].z)); m3 = fmaxf(m3, b2f(v[j].w));
        }
    }
    for (; e + 2 <= e1; e += 2) {
        int pa = ep1[e], pb = ep1[e + 1];
        ushort4 va = *(const ushort4*)&xw1[(size_t)(pa + lane4)];
        ushort4 vb = *(const ushort4*)&xw1[(size_t)(pb + lane4)];
        m0 = fmaxf(m0, fmaxf(b2f(va.x), b2f(vb.x)));
        m1 = fmaxf(m1, fmaxf(b2f(va.y), b2f(vb.y)));
        m2 = fmaxf(m2, fmaxf(b2f(va.z), b2f(vb.z)));
        m3 = fmaxf(m3, fmaxf(b2f(va.w), b2f(vb.w)));
    }
    for (; e < e1; e++) {
        int p = ep1[e];
        ushort4 v = *(const ushort4*)&xw1[(size_t)(p + lane4)];
        m0 = fmaxf(m0, b2f(v.x)); m1 = fmaxf(m1, b2f(v.y));
        m2 = fmaxf(m2, b2f(v.z)); m3 = fmaxf(m3, b2f(v.w));
    }
    if (e1 == e0) { m0 = m1 = m2 = m3 = 0.f; }

    ushort4 rt = *(const ushort4*)&xw1[(size_t)n * N1 + NREL * D_HID + lane4];
    int c = lane4;
    float t0 = m0 + b2f(rt.x) + bias[c + 0];
    float t1 = m1 + b2f(rt.y) + bias[c + 1];
    float t2 = m2 + b2f(rt.z) + bias[c + 2];
    float t3 = m3 + b2f(rt.w) + bias[c + 3];

    float s = t0 + t1 + t2 + t3;
    float s2 = t0 * t0 + t1 * t1 + t2 * t2 + t3 * t3;
    #pragma unroll
    for (int m = 32; m >= 1; m >>= 1) {
        s  += __shfl_xor(s,  m, 64);
        s2 += __shfl_xor(s2, m, 64);
    }
    float mu = s * (1.f / D_HID);
    float var = s2 * (1.f / D_HID) - mu * mu;
    float rs = rsqrtf(var + LN_EPS);

    ushort4 o;
    o.x = f2b(fmaxf((t0 - mu) * rs * g[c + 0] + b[c + 0], 0.f));
    o.y = f2b(fmaxf((t1 - mu) * rs * g[c + 1] + b[c + 1], 0.f));
    o.z = f2b(fmaxf((t2 - mu) * rs * g[c + 2] + b[c + 2], 0.f));
    o.w = f2b(fmaxf((t3 - mu) * rs * g[c + 3] + b[c + 3], 0.f));
    *(ushort4*)&h[(size_t)n * D_HID + c] = o;
}

// ---------- gather2: sum over in-edges + root + bias -> LN -> log_softmax -> out ----------
__global__ __launch_bounds__(256) void gather2(
    const ushort* __restrict__ xw2, const int* __restrict__ offs, const int* __restrict__ ep1,
    const float* __restrict__ bias, const float* __restrict__ g, const float* __restrict__ b,
    float* __restrict__ out)
{
    int n = blockIdx.x * 4 + (threadIdx.x >> 6);
    if (n >= NN) return;
    int lane = threadIdx.x & 63;
    int e0 = __builtin_amdgcn_readfirstlane(offs[n]);
    int e1 = __builtin_amdgcn_readfirstlane(offs[n + 1]);

    float s = 0.f;
    int e = e0;
    for (; e + 8 <= e1; e += 8) {
        int p[8];
        #pragma unroll
        for (int j = 0; j < 8; j++) p[j] = ep1[e + j] >> 2;
        float a[8];
        #pragma unroll
        for (int j = 0; j < 8; j++) a[j] = b2f(xw2[(size_t)(p[j] + lane)]);
        s += ((a[0] + a[1]) + (a[2] + a[3])) + ((a[4] + a[5]) + (a[6] + a[7]));
    }
    for (; e < e1; e++) {
        s += b2f(xw2[(size_t)((ep1[e] >> 2) + lane)]);
    }
    float v = s + b2f(xw2[(size_t)n * N2 + NREL * D_OUT + lane]) + bias[lane];

    float sm = v, s2 = v * v;
    #pragma unroll
    for (int m = 32; m >= 1; m >>= 1) {
        sm += __shfl_xor(sm, m, 64);
        s2 += __shfl_xor(s2, m, 64);
    }
    float mu = sm * (1.f / D_OUT);
    float var = s2 * (1.f / D_OUT) - mu * mu;
    float y = (v - mu) * rsqrtf(var + LN_EPS) * g[lane] + b[lane];

    float mx = y;
    #pragma unroll
    for (int m = 32; m >= 1; m >>= 1) mx = fmaxf(mx, __shfl_xor(mx, m, 64));
    float ex = __expf(y - mx);
    float se = ex;
    #pragma unroll
    for (int m = 32; m >= 1; m >>= 1) se += __shfl_xor(se, m, 64);
    out[(size_t)n * D_OUT + lane] = y - mx - logf(se);
}

extern "C" void kernel_launch(void* const* d_in, const int* in_sizes, int n_in,
                              void* d_out, int out_size, void* d_ws, size_t ws_size,
                              hipStream_t stream)
{
    const float* x      = (const float*)d_in[0];
    const int*   eidx   = (const int*)  d_in[1];
    const int*   etype  = (const int*)  d_in[2];
    const float* bases1 = (const float*)d_in[3];
    const float* comp1  = (const float*)d_in[4];
    const float* root1  = (const float*)d_in[5];
    const float* bias1  = (const float*)d_in[6];
    const float* g1     = (const float*)d_in[7];
    const float* b1     = (const float*)d_in[8];
    const float* bases2 = (const float*)d_in[9];
    const float* comp2  = (const float*)d_in[10];
    const float* root2  = (const float*)d_in[11];
    const float* bias2  = (const float*)d_in[12];
    const float* g2     = (const float*)d_in[13];
    const float* b2     = (const float*)d_in[14];

    const int* src = eidx;
    const int* dst = eidx + NE;

    char* p = (char*)d_ws;
    auto alloc = [&](size_t bytes) -> char* {
        char* r = p;
        p += (bytes + 255) & ~(size_t)255;
        return r;
    };
    ushort* xbf    = (ushort*)alloc((size_t)NN * D_IN * 2);
    ushort* w1t    = (ushort*)alloc((size_t)N1 * D_IN * 2);
    ushort* w2t    = (ushort*)alloc((size_t)N2 * D_HID * 2);
    ushort* xw1    = (ushort*)alloc((size_t)NN * N1 * 2);
    ushort* xw2    = (ushort*)alloc((size_t)NN * N2 * 2);
    ushort* h      = (ushort*)alloc((size_t)NN * D_HID * 2);
    int*    deg    = (int*)   alloc((size_t)NN * 4);
    int*    local  = (int*)   alloc((size_t)NN * 4);
    int*    bsum   = (int*)   alloc((size_t)NBLK * 4);
    int*    offs   = (int*)   alloc((size_t)(NN + 1) * 4);
    int*    cursor = (int*)   alloc((size_t)NN * 4);
    int*    ep1    = (int*)   alloc((size_t)NE * 4);

    hipMemsetAsync(deg, 0, (size_t)NN * 4, stream);
    const int SZP = D_IN * D_HID + D_HID * D_OUT + NN * D_IN + NE;
    prep_all<<<(SZP + 255) / 256, 256, 0, stream>>>(
        bases1, comp1, root1, bases2, comp2, root2, x, dst, w1t, w2t, xbf, deg);

    scan_blk<<<NBLK, 256, 0, stream>>>(deg, local, bsum);
    scan_fin<<<NBLK, 256, 0, stream>>>(local, bsum, offs, cursor);
    scatter_ep<<<(NE + 255) / 256, 256, 0, stream>>>(src, dst, etype, cursor, ep1);

    gemm_bf16<<<dim3(N1 / 128, (NN + 127) / 128), 256, 0, stream>>>(xbf, w1t, xw1, NN, N1, D_IN);
    gather1<<<(NN + 3) / 4, 256, 0, stream>>>(xw1, offs, ep1, bias1, g1, b1, h);

    gemm_bf16<<<dim3(N2 / 128, (NN + 127) / 128), 256, 0, stream>>>(h, w2t, xw2, NN, N2, D_HID);
    gather2<<<(NN + 3) / 4, 256, 0, stream>>>(xw2, offs, ep1, bias2, g2, b2, (float*)d_out);
}